// Round 1
// baseline (14290.637 us; speedup 1.0000x reference)
//
#include <hip/hip_runtime.h>

#define Bv 128
#define Tv 256
#define Vv 512
#define Hv 1024
#define FH 4096   // 4*H
#define TD 255    // T-1 decoder steps

typedef unsigned short ushort_t;
typedef __attribute__((ext_vector_type(8))) short bf16x8;
typedef __attribute__((ext_vector_type(4))) float f32x4;

__device__ __forceinline__ ushort_t f2bf(float f) {
    unsigned u = __float_as_uint(f);
    unsigned r = (u + 0x7fffu + ((u >> 16) & 1u)) >> 16;
    return (ushort_t)r;
}
__device__ __forceinline__ float bf2f(ushort_t h) {
    return __uint_as_float(((unsigned)h) << 16);
}
__device__ __forceinline__ float sigm(float x) {
    return 1.0f / (1.0f + expf(-x));
}

// ---------------------------------------------------------------------------
// Split W [K][N] fp32 into transposed hi/lo bf16 [N][K]
// grid (N/64, K/32), 256 threads
// ---------------------------------------------------------------------------
__global__ __launch_bounds__(256) void wsplit_t(
    const float* __restrict__ W, int K, int N,
    ushort_t* __restrict__ hiT, ushort_t* __restrict__ loT)
{
    __shared__ float ts[32][65];
    const int n0 = blockIdx.x * 64, k0 = blockIdx.y * 32;
    const int tid = threadIdx.x;
#pragma unroll
    for (int i = 0; i < 8; i++) {
        int f = tid + i * 256;
        int k = f >> 6, nn = f & 63;
        ts[k][nn] = W[(size_t)(k0 + k) * N + n0 + nn];
    }
    __syncthreads();
#pragma unroll
    for (int i = 0; i < 8; i++) {
        int f = tid + i * 256;
        int nn = f >> 5, k = f & 31;
        float v = ts[k][nn];
        ushort_t h = f2bf(v);
        ushort_t l = f2bf(v - bf2f(h));
        size_t o = (size_t)(n0 + nn) * K + k0 + k;
        hiT[o] = h;
        loT[o] = l;
    }
}

// ---------------------------------------------------------------------------
// One-hot [rows][512] -> token index. One wave per row.
// ---------------------------------------------------------------------------
__global__ __launch_bounds__(256) void extract_tokens(
    const float* __restrict__ x, int* __restrict__ tok)
{
    int row = blockIdx.x * 4 + (threadIdx.x >> 6);
    int lane = threadIdx.x & 63;
    const float* p = x + (size_t)row * Vv;
    int found = -1;
#pragma unroll
    for (int i = 0; i < 8; i++)
        if (p[lane + i * 64] > 0.5f) found = lane + i * 64;
#pragma unroll
    for (int off = 32; off > 0; off >>= 1) {
        int o = __shfl_down(found, off);
        found = found > o ? found : o;
    }
    if (lane == 0) tok[row] = found;
}

// ---------------------------------------------------------------------------
// First position where enc token == EOS(1); idx = eos_pos (or T-1 if absent)
// ---------------------------------------------------------------------------
__global__ void find_eos(const int* __restrict__ tok, int* __restrict__ idx)
{
    int b = threadIdx.x;
    int first = Tv - 1;
    for (int t = Tv - 1; t >= 0; t--)
        if (tok[b * Tv + t] == 1) first = t;
    idx[b] = first;
}

// ---------------------------------------------------------------------------
// One LSTM step. grid (64 j-tiles, 4 b-tiles), 256 threads (4 waves).
// wave tile: 16 batches x 32 cols; block tile 32 b x 64 cols
// (cols = 16 j x 4 gates interleaved: local col c -> gate g=c>>4, j'=c&15).
// z = hin @ Wh via bf16x3 split MFMA; then gates fused in epilogue.
// ---------------------------------------------------------------------------
__global__ __launch_bounds__(256) void lstm_step(
    const ushort_t* __restrict__ WhiT, const ushort_t* __restrict__ WloT, // [4096][1024]
    const float* __restrict__ Wi,      // [512][4096] fp32 (exact gather)
    const float* __restrict__ bias,    // [4096]
    const int* __restrict__ tok, int t,
    const ushort_t* __restrict__ hin_hi, const ushort_t* __restrict__ hin_lo, // [B][H]
    ushort_t* __restrict__ hout_hi, ushort_t* __restrict__ hout_lo,
    float* __restrict__ c_state,       // [B][H] in/out (exact fp32)
    ushort_t* __restrict__ hex_hi, ushort_t* __restrict__ hex_lo,   // nullable: hd slice
    const int* __restrict__ save_idx,                               // nullable: encoder save
    float* __restrict__ c_save, ushort_t* __restrict__ hs_hi, ushort_t* __restrict__ hs_lo)
{
    __shared__ float z_s[32][68];
    const int tid = threadIdx.x;
    const int wave = tid >> 6, lane = tid & 63;
    const int wm = wave & 1, wn = wave >> 1;
    const int n = lane & 15, quad = lane >> 4;
    const int j0 = blockIdx.x * 16;
    const int b0 = blockIdx.y * 32;

    // A fragment source: h row (batch), 8 consecutive k per lane
    const size_t arow = (size_t)(b0 + wm * 16 + n) * Hv + quad * 8;
    // B fragment source: transposed weight rows for the two gate-subtiles
    const size_t g0 = (size_t)((2 * wn + 0) * Hv + j0 + n) * Hv + quad * 8;
    const size_t g1 = (size_t)((2 * wn + 1) * Hv + j0 + n) * Hv + quad * 8;

    f32x4 acc0 = {0.f, 0.f, 0.f, 0.f}, acc1 = {0.f, 0.f, 0.f, 0.f};

#pragma unroll 2
    for (int kc = 0; kc < Hv; kc += 32) {
        bf16x8 ahi = *(const bf16x8*)(hin_hi + arow + kc);
        bf16x8 alo = *(const bf16x8*)(hin_lo + arow + kc);
        bf16x8 b0h = *(const bf16x8*)(WhiT + g0 + kc);
        bf16x8 b0l = *(const bf16x8*)(WloT + g0 + kc);
        bf16x8 b1h = *(const bf16x8*)(WhiT + g1 + kc);
        bf16x8 b1l = *(const bf16x8*)(WloT + g1 + kc);
        acc0 = __builtin_amdgcn_mfma_f32_16x16x32_bf16(ahi, b0h, acc0, 0, 0, 0);
        acc1 = __builtin_amdgcn_mfma_f32_16x16x32_bf16(ahi, b1h, acc1, 0, 0, 0);
        acc0 = __builtin_amdgcn_mfma_f32_16x16x32_bf16(alo, b0h, acc0, 0, 0, 0);
        acc1 = __builtin_amdgcn_mfma_f32_16x16x32_bf16(alo, b1h, acc1, 0, 0, 0);
        acc0 = __builtin_amdgcn_mfma_f32_16x16x32_bf16(ahi, b0l, acc0, 0, 0, 0);
        acc1 = __builtin_amdgcn_mfma_f32_16x16x32_bf16(ahi, b1l, acc1, 0, 0, 0);
    }

    // C/D layout: col = lane&15, row = quad*4 + r  -> scatter to LDS for gate exchange
    const int row0 = wm * 16 + quad * 4;
    const int cb0 = (2 * wn + 0) * 16 + n;
    const int cb1 = cb0 + 16;
#pragma unroll
    for (int r = 0; r < 4; r++) {
        z_s[row0 + r][cb0] = acc0[r];
        z_s[row0 + r][cb1] = acc1[r];
    }
    __syncthreads();

#pragma unroll
    for (int i = 0; i < 2; i++) {
        int p = tid + i * 256;
        int bl = p >> 4, jl = p & 15;
        int b = b0 + bl, col = j0 + jl;
        int tk = tok[b * Tv + t];
        const float* wr = Wi + (size_t)tk * FH + col;
        float zi = z_s[bl][jl]      + wr[0]        + bias[col];
        float zf = z_s[bl][16 + jl] + wr[Hv]       + bias[Hv + col];
        float zg = z_s[bl][32 + jl] + wr[2 * Hv]   + bias[2 * Hv + col];
        float zo = z_s[bl][48 + jl] + wr[3 * Hv]   + bias[3 * Hv + col];
        float si = sigm(zi), sf = sigm(zf), so = sigm(zo);
        float gg = tanhf(zg);
        size_t off = (size_t)b * Hv + col;
        float cn = sf * c_state[off] + si * gg;
        float hn = so * tanhf(cn);
        c_state[off] = cn;
        ushort_t hh = f2bf(hn);
        ushort_t hl = f2bf(hn - bf2f(hh));
        hout_hi[off] = hh;
        hout_lo[off] = hl;
        if (hex_hi) { hex_hi[off] = hh; hex_lo[off] = hl; }
        if (save_idx) {
            if (t == save_idx[b]) { c_save[off] = cn; hs_hi[off] = hh; hs_lo[off] = hl; }
        }
    }
}

// ---------------------------------------------------------------------------
// logits = hd @ dense_W + b : [32640,1024] x [1024,512], bf16x3 MFMA.
// grid (8, 1020), 256 threads; block 32 m x 64 n; wave 16 m x 32 n.
// row r = t*B + b ; out index = (b*TD + t)*V + col
// ---------------------------------------------------------------------------
__global__ __launch_bounds__(256) void dense_mfma(
    const ushort_t* __restrict__ Ahi, const ushort_t* __restrict__ Alo, // [32640][1024]
    const ushort_t* __restrict__ WhiT, const ushort_t* __restrict__ WloT, // [512][1024]
    const float* __restrict__ bias, float* __restrict__ out)
{
    const int tid = threadIdx.x;
    const int wave = tid >> 6, lane = tid & 63;
    const int wm = wave & 1, wn = wave >> 1;
    const int n = lane & 15, quad = lane >> 4;
    const int m0 = blockIdx.y * 32 + wm * 16;
    const int c0 = blockIdx.x * 64 + wn * 32;

    const size_t arow = (size_t)(m0 + n) * Hv + quad * 8;
    const size_t g0 = (size_t)(c0 + 0 + n) * Hv + quad * 8;
    const size_t g1 = (size_t)(c0 + 16 + n) * Hv + quad * 8;

    f32x4 acc0 = {0.f, 0.f, 0.f, 0.f}, acc1 = {0.f, 0.f, 0.f, 0.f};

#pragma unroll 2
    for (int kc = 0; kc < Hv; kc += 32) {
        bf16x8 ahi = *(const bf16x8*)(Ahi + arow + kc);
        bf16x8 alo = *(const bf16x8*)(Alo + arow + kc);
        bf16x8 b0h = *(const bf16x8*)(WhiT + g0 + kc);
        bf16x8 b0l = *(const bf16x8*)(WloT + g0 + kc);
        bf16x8 b1h = *(const bf16x8*)(WhiT + g1 + kc);
        bf16x8 b1l = *(const bf16x8*)(WloT + g1 + kc);
        acc0 = __builtin_amdgcn_mfma_f32_16x16x32_bf16(ahi, b0h, acc0, 0, 0, 0);
        acc1 = __builtin_amdgcn_mfma_f32_16x16x32_bf16(ahi, b1h, acc1, 0, 0, 0);
        acc0 = __builtin_amdgcn_mfma_f32_16x16x32_bf16(alo, b0h, acc0, 0, 0, 0);
        acc1 = __builtin_amdgcn_mfma_f32_16x16x32_bf16(alo, b1h, acc1, 0, 0, 0);
        acc0 = __builtin_amdgcn_mfma_f32_16x16x32_bf16(ahi, b0l, acc0, 0, 0, 0);
        acc1 = __builtin_amdgcn_mfma_f32_16x16x32_bf16(ahi, b1l, acc1, 0, 0, 0);
    }

#pragma unroll
    for (int r = 0; r < 4; r++) {
        int row = m0 + quad * 4 + r;
        int tt = row >> 7, bb = row & 127;
        size_t o = ((size_t)bb * TD + tt) * Vv;
        int col0 = c0 + n, col1 = c0 + 16 + n;
        out[o + col0] = acc0[r] + bias[col0];
        out[o + col1] = acc1[r] + bias[col1];
    }
}

// ---------------------------------------------------------------------------
extern "C" void kernel_launch(void* const* d_in, const int* in_sizes, int n_in,
                              void* d_out, int out_size, void* d_ws, size_t ws_size,
                              hipStream_t stream)
{
    const float* enc_in  = (const float*)d_in[0];
    const float* dec_in  = (const float*)d_in[1];
    const float* enc_Wi  = (const float*)d_in[2];
    const float* enc_Wh  = (const float*)d_in[3];
    const float* enc_b   = (const float*)d_in[4];
    const float* dec_Wi  = (const float*)d_in[5];
    const float* dec_Wh  = (const float*)d_in[6];
    const float* dec_b   = (const float*)d_in[7];
    const float* dense_W = (const float*)d_in[8];
    const float* dense_b = (const float*)d_in[9];
    float* out = (float*)d_out;

    char* wp = (char*)d_ws;
    auto take = [&](size_t bytes) -> char* {
        char* p = wp;
        wp += (bytes + 255) & ~(size_t)255;
        return p;
    };

    ushort_t* hd_hi = (ushort_t*)take((size_t)TD * Bv * Hv * 2);
    ushort_t* hd_lo = (ushort_t*)take((size_t)TD * Bv * Hv * 2);
    ushort_t* eWhi  = (ushort_t*)take((size_t)FH * Hv * 2);
    ushort_t* eWlo  = (ushort_t*)take((size_t)FH * Hv * 2);
    ushort_t* dWhi  = (ushort_t*)take((size_t)FH * Hv * 2);
    ushort_t* dWlo  = (ushort_t*)take((size_t)FH * Hv * 2);
    ushort_t* nWhi  = (ushort_t*)take((size_t)Vv * Hv * 2);
    ushort_t* nWlo  = (ushort_t*)take((size_t)Vv * Hv * 2);
    ushort_t* hbh0  = (ushort_t*)take((size_t)Bv * Hv * 2);
    ushort_t* hbl0  = (ushort_t*)take((size_t)Bv * Hv * 2);
    ushort_t* hbh1  = (ushort_t*)take((size_t)Bv * Hv * 2);
    ushort_t* hbl1  = (ushort_t*)take((size_t)Bv * Hv * 2);
    ushort_t* hshi  = (ushort_t*)take((size_t)Bv * Hv * 2);
    ushort_t* hslo  = (ushort_t*)take((size_t)Bv * Hv * 2);
    float*    c_state = (float*)take((size_t)Bv * Hv * 4);
    float*    c_save  = (float*)take((size_t)Bv * Hv * 4);
    int*      etok  = (int*)take((size_t)Bv * Tv * 4);
    int*      dtok  = (int*)take((size_t)Bv * Tv * 4);
    int*      eidx  = (int*)take((size_t)Bv * 4);

    ushort_t* hbh[2] = {hbh0, hbh1};
    ushort_t* hbl[2] = {hbl0, hbl1};

    // --- preprocess: weight split+transpose, token extraction, lengths -----
    wsplit_t<<<dim3(FH / 64, Hv / 32), 256, 0, stream>>>(enc_Wh, Hv, FH, eWhi, eWlo);
    wsplit_t<<<dim3(FH / 64, Hv / 32), 256, 0, stream>>>(dec_Wh, Hv, FH, dWhi, dWlo);
    wsplit_t<<<dim3(Vv / 64, Hv / 32), 256, 0, stream>>>(dense_W, Hv, Vv, nWhi, nWlo);
    extract_tokens<<<Bv * Tv / 4, 256, 0, stream>>>(enc_in, etok);
    extract_tokens<<<Bv * Tv / 4, 256, 0, stream>>>(dec_in, dtok);
    find_eos<<<1, Bv, 0, stream>>>(etok, eidx);

    hipMemsetAsync(hbh0, 0, (size_t)Bv * Hv * 2, stream);
    hipMemsetAsync(hbl0, 0, (size_t)Bv * Hv * 2, stream);
    hipMemsetAsync(c_state, 0, (size_t)Bv * Hv * 4, stream);

    // --- encoder: 256 steps, save state at t == eos_idx[b] ------------------
    for (int t = 0; t < Tv; t++) {
        lstm_step<<<dim3(64, 4), 256, 0, stream>>>(
            eWhi, eWlo, enc_Wi, enc_b, etok, t,
            hbh[t & 1], hbl[t & 1], hbh[(t + 1) & 1], hbl[(t + 1) & 1],
            c_state, nullptr, nullptr, eidx, c_save, hshi, hslo);
    }

    // --- phase switch: decoder initial state = saved encoder state ---------
    hipMemcpyAsync(c_state, c_save, (size_t)Bv * Hv * 4, hipMemcpyDeviceToDevice, stream);
    hipMemcpyAsync(hbh0, hshi, (size_t)Bv * Hv * 2, hipMemcpyDeviceToDevice, stream);
    hipMemcpyAsync(hbl0, hslo, (size_t)Bv * Hv * 2, hipMemcpyDeviceToDevice, stream);

    // --- decoder: 255 steps, store h (split) for dense GEMM -----------------
    for (int t = 0; t < TD; t++) {
        lstm_step<<<dim3(64, 4), 256, 0, stream>>>(
            dWhi, dWlo, dec_Wi, dec_b, dtok, t,
            hbh[t & 1], hbl[t & 1], hbh[(t + 1) & 1], hbl[(t + 1) & 1],
            c_state, hd_hi + (size_t)t * Bv * Hv, hd_lo + (size_t)t * Bv * Hv,
            nullptr, nullptr, nullptr, nullptr);
    }

    // --- dense head ---------------------------------------------------------
    dense_mfma<<<dim3(Vv / 64, (TD * Bv) / 32), 256, 0, stream>>>(
        hd_hi, hd_lo, nWhi, nWlo, dense_b, out);
}